// Round 1
// baseline (908.519 us; speedup 1.0000x reference)
//
#include <hip/hip_runtime.h>
#include <math.h>

#define E   100
#define EP  104   // padded E (zero pads)
#define V   3
#define S   100
#define SP  102   // xs row pitch / padded S rows
#define T   10
#define NB  8192
#define SCALE 0.1f
#define PADV  (-4294967295.0f)

// ws float-offset layout (prep kernel outputs)
#define WS_W1T 0        // [k<100][e<104] transposed fc1_w, zero-padded
#define WS_W4T 10400    // [k<100][e<104] transposed fc4_w
#define WS_OF2 20800    // [v<3][e<104]  of2 = vk@fc2_w.T + fc2_b, zero-padded
#define WS_OF3 21112    // [v<3][e<104]
#define WS_B1  21424    // [e<104] fc1_b zero-padded
#define WS_B4  21528    // [e<104] fc4_b zero-padded
// total 21632 floats = 86.5 KB of d_ws

__global__ void prep_kernel(const float* __restrict__ vk,
                            const float* __restrict__ fc1w, const float* __restrict__ fc1b,
                            const float* __restrict__ fc2w, const float* __restrict__ fc2b,
                            const float* __restrict__ fc3w, const float* __restrict__ fc3b,
                            const float* __restrict__ fc4w, const float* __restrict__ fc4b,
                            float* __restrict__ ws) {
    int g = blockIdx.x * blockDim.x + threadIdx.x;
    if (g < 100 * EP) {                      // transpose W1, W4 with zero pad on e
        int k = g / EP, e = g % EP;
        float w1 = 0.f, w4 = 0.f;
        if (e < E) { w1 = fc1w[e * E + k]; w4 = fc4w[e * E + k]; }
        ws[WS_W1T + g] = w1;
        ws[WS_W4T + g] = w4;
    }
    if (g < 2 * V * EP) {                    // of2, of3 (tiny GEMVs)
        int which = g / (V * EP);
        int r = g % (V * EP);
        int v = r / EP, e = r % EP;
        float val = 0.f;
        if (e < E) {
            const float* w  = which ? fc3w : fc2w;
            const float* bb = which ? fc3b : fc2b;
            float acc = bb[e];
            for (int k = 0; k < E; ++k) acc += vk[v * E + k] * w[e * E + k];
            val = acc;
        }
        ws[(which ? WS_OF3 : WS_OF2) + r] = val;
    }
    if (g < 2 * EP) {                        // padded biases
        int which = g / EP, e = g % EP;
        float val = 0.f;
        if (e < E) val = which ? fc4b[e] : fc1b[e];
        ws[(which ? WS_B4 : WS_B1) + e] = val;
    }
}

// One block per batch b. 256 threads.
// GEMM mapping: tx = t%13 -> 8 e-cols (e=8tx..8tx+7, covers 104 padded),
//               ty = t/13 -> 6 s-rows (s=6ty..6ty+5, ty<17 covers 102 padded rows).
__global__ __launch_bounds__(256) void mvke_main(const float* __restrict__ x,
                                                 const float* __restrict__ tag,
                                                 const float* __restrict__ ws,
                                                 float* __restrict__ out) {
    __shared__ __align__(16) float uni[SP * SP];   // 10404 f: xs -> P -> W2 -> P2 -> P3
    __shared__ __align__(16) float tag_l[T * EP];  // 1040 f
    __shared__ float smask[S];                     // 100 f
    __shared__ float m1_l[S * V];                  // 300 f
    __shared__ float sm1_l[SP * V];                // 306 f (rows 100,101 zeroed)
    __shared__ float ws1_l[V * EP];                // 312 f
    __shared__ float m2_l[T * V];                  // 30 f
    __shared__ float sm2_l[T * V];                 // 30 f

    const int t = threadIdx.x;
    const int b = blockIdx.x;
    const float* xb = x   + (size_t)b * (S * E);
    const float* tb = tag + (size_t)b * (T * E);

    float* xs = uni;   // [s<102][k], pitch SP=102

    // ---- stage x[b] into LDS (coalesced float4 reads, float2 LDS writes) ----
    for (int i = t; i < S * E / 4; i += 256) {     // 2500 float4s
        int s = i / 25, kk = (i % 25) * 4;
        float4 v = *(const float4*)(xb + s * E + kk);
        float* d = &xs[s * SP + kk];
        *(float2*)(d)     = make_float2(v.x, v.y);
        *(float2*)(d + 2) = make_float2(v.z, v.w);
    }
    for (int i = t; i < 2 * SP; i += 256) xs[S * SP + i] = 0.f;  // zero rows 100,101
    // tag[b] -> LDS, pitch EP, zero pads
    for (int i = t; i < T * E / 4; i += 256) {     // 250 float4s
        int s = i / 25, kk = (i % 25) * 4;
        float4 v = *(const float4*)(tb + s * E + kk);
        *(float4*)(&tag_l[s * EP + kk]) = v;
    }
    if (t < T * 4) { int s = t / 4; tag_l[s * EP + E + (t % 4)] = 0.f; }
    if (t < 2 * V) sm1_l[S * V + t] = 0.f;         // sm1 pad rows
    __syncthreads();

    const int tx = t % 13;
    const int ty = t / 13;
    const bool act = (t < 221);                    // 13*17

    // ---- row |x| sums for the padding mask (reads xs) ----
    if (t < S) {
        float ra = 0.f;
        for (int k = 0; k < E; k += 2) {
            float2 a2 = *(const float2*)(&xs[t * SP + k]);
            ra += fabsf(a2.x) + fabsf(a2.y);
        }
        smask[t] = ra;
    }

    // ---- Phase 1: of1 tile in registers: C[i][j] = of1[6ty+i][8tx+j] ----
    float C[6][8];
    if (act) {
        #pragma unroll
        for (int i = 0; i < 6; ++i)
            #pragma unroll
            for (int j = 0; j < 8; ++j) C[i][j] = 0.f;

        const float* w1tp = ws + WS_W1T + 8 * tx;
        const float* xrow = &xs[(6 * ty) * SP];
        #pragma unroll 2
        for (int k = 0; k < E; k += 2) {
            float4 qa0 = *(const float4*)(w1tp + k * EP);
            float4 qb0 = *(const float4*)(w1tp + k * EP + 4);
            float4 qa1 = *(const float4*)(w1tp + (k + 1) * EP);
            float4 qb1 = *(const float4*)(w1tp + (k + 1) * EP + 4);
            float w0[8] = {qa0.x, qa0.y, qa0.z, qa0.w, qb0.x, qb0.y, qb0.z, qb0.w};
            float w1[8] = {qa1.x, qa1.y, qa1.z, qa1.w, qb1.x, qb1.y, qb1.z, qb1.w};
            #pragma unroll
            for (int i = 0; i < 6; ++i) {
                float2 a = *(const float2*)(xrow + i * SP + k);
                #pragma unroll
                for (int j = 0; j < 8; ++j) C[i][j] += a.x * w0[j] + a.y * w1[j];
            }
        }
        const float* b1p = ws + WS_B1 + 8 * tx;
        float bb[8];
        #pragma unroll
        for (int j = 0; j < 8; ++j) bb[j] = b1p[j];
        #pragma unroll
        for (int i = 0; i < 6; ++i)
            #pragma unroll
            for (int j = 0; j < 8; ++j) C[i][j] += bb[j];
    }
    __syncthreads();   // xs dead; uni reusable

    // ---- Phase 2: m1 partials P[s][v][tx13] ----
    float* P = uni;    // s*39 + v*13 + tx  (3900 floats)
    if (act) {
        const float* of2g = ws + WS_OF2 + 8 * tx;
        float o2[V][8];
        #pragma unroll
        for (int v = 0; v < V; ++v)
            #pragma unroll
            for (int j = 0; j < 8; ++j) o2[v][j] = of2g[v * EP + j];
        #pragma unroll
        for (int i = 0; i < 6; ++i) {
            int s = 6 * ty + i;
            if (s < S) {
                float p0 = 0.f, p1 = 0.f, p2 = 0.f;
                #pragma unroll
                for (int j = 0; j < 8; ++j) {
                    p0 += C[i][j] * o2[0][j];
                    p1 += C[i][j] * o2[1][j];
                    p2 += C[i][j] * o2[2][j];
                }
                P[s * 39 + tx]      = p0;
                P[s * 39 + 13 + tx] = p1;
                P[s * 39 + 26 + tx] = p2;
            }
        }
    }
    __syncthreads();
    for (int o = t; o < S * V; o += 256) {         // reduce over tx, mask, scale
        int s = o / V, v = o % V;
        float acc = 0.f;
        for (int c = 0; c < 13; ++c) acc += P[s * 39 + v * 13 + c];
        m1_l[o] = (smask[s] == 0.f) ? PADV : acc * SCALE;
    }
    __syncthreads();

    // ---- softmax over S per v (3 waves) ----
    {
        int wv = t >> 6, lane = t & 63;
        if (wv < V) {
            float x1 = m1_l[lane * V + wv];
            int s2 = lane + 64;
            float x2 = (s2 < S) ? m1_l[s2 * V + wv] : -INFINITY;
            float mx = fmaxf(x1, x2);
            for (int d = 32; d > 0; d >>= 1) mx = fmaxf(mx, __shfl_xor(mx, d));
            float e1 = __expf(x1 - mx);
            float e2 = (s2 < S) ? __expf(x2 - mx) : 0.f;
            float sm = e1 + e2;
            for (int d = 32; d > 0; d >>= 1) sm += __shfl_xor(sm, d);
            float inv = 1.f / sm;
            sm1_l[lane * V + wv] = e1 * inv;
            if (s2 < S) sm1_l[s2 * V + wv] = e2 * inv;
        }
    }
    __syncthreads();

    // ---- Phase 3: ws1 partials over ty groups ----
    float* W2 = uni;   // [(g*3+v)*EP + e]  g<17 -> 5304 floats
    if (act) {
        float a0[8], a1[8], a2[8];
        #pragma unroll
        for (int j = 0; j < 8; ++j) { a0[j] = 0.f; a1[j] = 0.f; a2[j] = 0.f; }
        #pragma unroll
        for (int i = 0; i < 6; ++i) {
            int s = 6 * ty + i;                    // s < 102, sm1_l padded with zeros
            float s0 = sm1_l[s * V + 0];
            float s1 = sm1_l[s * V + 1];
            float s2 = sm1_l[s * V + 2];
            #pragma unroll
            for (int j = 0; j < 8; ++j) {
                a0[j] += s0 * C[i][j];
                a1[j] += s1 * C[i][j];
                a2[j] += s2 * C[i][j];
            }
        }
        float* w2r = &W2[(ty * 3) * EP + 8 * tx];
        *(float4*)(w2r)              = make_float4(a0[0], a0[1], a0[2], a0[3]);
        *(float4*)(w2r + 4)          = make_float4(a0[4], a0[5], a0[6], a0[7]);
        *(float4*)(w2r + EP)         = make_float4(a1[0], a1[1], a1[2], a1[3]);
        *(float4*)(w2r + EP + 4)     = make_float4(a1[4], a1[5], a1[6], a1[7]);
        *(float4*)(w2r + 2 * EP)     = make_float4(a2[0], a2[1], a2[2], a2[3]);
        *(float4*)(w2r + 2 * EP + 4) = make_float4(a2[4], a2[5], a2[6], a2[7]);
    }
    __syncthreads();
    for (int o = t; o < V * EP; o += 256) {        // reduce over 17 groups
        int v = o / EP, e = o % EP;
        float acc = 0.f;
        if (e < E) for (int g = 0; g < 17; ++g) acc += W2[(g * 3 + v) * EP + e];
        ws1_l[o] = acc;
    }
    __syncthreads();

    // ---- Phase 4: of4 (t<130: tx->8e, ty->t-row) + m2 partials ----
    float* P2 = uni;   // [(ty*3+v)*13 + tx]  390 floats
    const bool act4 = (t < 130);
    if (act4) {
        float D[8];
        #pragma unroll
        for (int j = 0; j < 8; ++j) D[j] = 0.f;
        const float* w4tp = ws + WS_W4T + 8 * tx;
        const float* trow = &tag_l[ty * EP];
        #pragma unroll 2
        for (int k = 0; k < E; k += 2) {
            float4 qa0 = *(const float4*)(w4tp + k * EP);
            float4 qb0 = *(const float4*)(w4tp + k * EP + 4);
            float4 qa1 = *(const float4*)(w4tp + (k + 1) * EP);
            float4 qb1 = *(const float4*)(w4tp + (k + 1) * EP + 4);
            float w0[8] = {qa0.x, qa0.y, qa0.z, qa0.w, qb0.x, qb0.y, qb0.z, qb0.w};
            float w1[8] = {qa1.x, qa1.y, qa1.z, qa1.w, qb1.x, qb1.y, qb1.z, qb1.w};
            float2 a = *(const float2*)(trow + k);
            #pragma unroll
            for (int j = 0; j < 8; ++j) D[j] += a.x * w0[j] + a.y * w1[j];
        }
        const float* b4p = ws + WS_B4 + 8 * tx;
        #pragma unroll
        for (int j = 0; j < 8; ++j) D[j] += b4p[j];

        const float* of3g = ws + WS_OF3 + 8 * tx;
        #pragma unroll
        for (int v = 0; v < V; ++v) {
            float pm = 0.f;
            #pragma unroll
            for (int j = 0; j < 8; ++j) pm += D[j] * of3g[v * EP + j];
            P2[(ty * 3 + v) * 13 + tx] = pm;
        }
    }
    __syncthreads();
    if (t < T * V) {
        int tt = t / V, v = t % V;
        float acc = 0.f;
        for (int c = 0; c < 13; ++c) acc += P2[(tt * 3 + v) * 13 + c];
        m2_l[tt * V + v] = acc * SCALE;
    }
    __syncthreads();
    if (t < V) {                                   // softmax over T (10) per v
        float mx = -INFINITY;
        for (int tt = 0; tt < T; ++tt) mx = fmaxf(mx, m2_l[tt * V + t]);
        float ee[T]; float sum = 0.f;
        for (int tt = 0; tt < T; ++tt) { ee[tt] = __expf(m2_l[tt * V + t] - mx); sum += ee[tt]; }
        float inv = 1.f / sum;
        for (int tt = 0; tt < T; ++tt) sm2_l[tt * V + t] = ee[tt] * inv;
    }
    __syncthreads();

    // ---- Phase 5: user_emb dot tag ----
    float* P3 = uni;   // [ty*13 + tx] 130 floats
    if (act4) {
        float s0 = sm2_l[ty * V + 0];
        float s1 = sm2_l[ty * V + 1];
        float s2 = sm2_l[ty * V + 2];
        float pe = 0.f;
        #pragma unroll
        for (int j = 0; j < 8; ++j) {
            int e = 8 * tx + j;
            float ue = s0 * ws1_l[e] + s1 * ws1_l[EP + e] + s2 * ws1_l[2 * EP + e];
            pe += ue * tag_l[ty * EP + e];
        }
        P3[ty * 13 + tx] = pe;
    }
    __syncthreads();
    if (t < T) {
        float acc = 0.f;
        for (int c = 0; c < 13; ++c) acc += P3[t * 13 + c];
        out[(size_t)b * T + t] = acc;
    }
}

extern "C" void kernel_launch(void* const* d_in, const int* in_sizes, int n_in,
                              void* d_out, int out_size, void* d_ws, size_t ws_size,
                              hipStream_t stream) {
    const float* x    = (const float*)d_in[0];
    const float* tag  = (const float*)d_in[1];
    const float* vk   = (const float*)d_in[2];
    const float* fc1w = (const float*)d_in[3];
    const float* fc1b = (const float*)d_in[4];
    const float* fc2w = (const float*)d_in[5];
    const float* fc2b = (const float*)d_in[6];
    const float* fc3w = (const float*)d_in[7];
    const float* fc3b = (const float*)d_in[8];
    const float* fc4w = (const float*)d_in[9];
    const float* fc4b = (const float*)d_in[10];
    float* out = (float*)d_out;
    float* ws  = (float*)d_ws;

    hipLaunchKernelGGL(prep_kernel, dim3(41), dim3(256), 0, stream,
                       vk, fc1w, fc1b, fc2w, fc2b, fc3w, fc3b, fc4w, fc4b, ws);
    hipLaunchKernelGGL(mvke_main, dim3(NB), dim3(256), 0, stream,
                       x, tag, ws, out);
}